// Round 16
// baseline (617.177 us; speedup 1.0000x reference)
//
#include <hip/hip_runtime.h>

#define T_STEPS 1000
#define BATCH   256
#define NHID    200
#define ROWF    200      // floats per LDS row (800 B, 16B-aligned)
#define BETA_C  0.85f
#define THR_C   1.0f
#define SENT    (1ull << 50)

// WT2 row i (source neuron i) holds at float offset lo*4+k (lo<50,k<4):
// Wrec[(lo+50k)][i]. Lane lo reads ONE ds_read_b128 per firing source i,
// yielding weights for outputs {lo, lo+50, lo+100, lo+150}.
//
// 4 waves per batch element; wave w gathers source word w (~7 firing) with
// an 8-wide sentinel-gated trip (one wait chain instead of 2-3), owns output
// word w. Parity-transposed exchange -> ONE lgkm-only barrier per step
// (round 15). Dummy slots: clamped in-bounds load, gate 0.0, fmaf(g,v,acc)
// is bit-exact. cur2 recomputed by a second kernel from stored spikes.

#define BARRIER_LGKM \
    asm volatile("s_waitcnt lgkmcnt(0)\n\ts_barrier" ::: "memory");

__launch_bounds__(256, 1)
__global__ void rsnn_kernel(const float* __restrict__ X,
                            const float* __restrict__ W1,
                            const float* __restrict__ b1,
                            const float* __restrict__ Wrec,
                            const float* __restrict__ brec,
                            float* __restrict__ out_spk) {
#pragma clang fp contract(off)
    __shared__ float WT2[NHID * ROWF];   // 160,000 B
    __shared__ float part[4][4][50];     //   3,200 B

    const int tid = threadIdx.x;
    const int l   = tid & 63;            // lane
    const int w   = tid >> 6;            // wave id = source & output word id
    const int b   = blockIdx.x;

    // ---- stage Wrec (permuted transpose) into LDS ----
    for (int idx = tid; idx < NHID * NHID; idx += 256) {
        int r  = idx / NHID;             // Wrec row  (output neuron)
        int i  = idx - r * NHID;         // Wrec col  (source neuron)
        int lo = r % 50, k = r / 50;
        WT2[i * ROWF + lo * 4 + k] = Wrec[idx];
    }
    __syncthreads();

    const int lc = (l < 50) ? l : 49;    // lanes 50-63 duplicate lane 49
    const int oc = 50 * w + lc;          // this lane's output neuron
    const float w10 = W1[oc * 3 + 0], w11 = W1[oc * 3 + 1], w12 = W1[oc * 3 + 2];
    const float b1j = b1[oc], brj = brec[oc];

    float mem = 0.f;
    unsigned long long bm = 0;           // own word's spike mask

    const float* xp = X + (size_t)b * 3;
    float x0 = xp[0], x1 = xp[1], x2 = xp[2];

    const float* ldsrow  = WT2 + (size_t)lc * 4;
    const int    wbase   = 50 * w;
    float*       spk_out = out_spk + (size_t)b * NHID + wbase + lc;

// 8-wide sentinel-gated slot: ctz always defined; dummy -> row 49 (in
// bounds), gate 0.0; fmaf with gate in {0,1} is bit-exact.
#define GSLOT(K)                                                       \
    unsigned long long mm##K = m | SENT;                               \
    int   r##K = __builtin_ctzll(mm##K);                               \
    int   i##K = r##K > 49 ? 49 : r##K;                                \
    float g##K = (m != 0ull) ? 1.f : 0.f;                              \
    m &= m - 1;                                                        \
    const float4 gv##K = *(const float4*)(ldsrow + (i##K + wbase) * ROWF);

#define GACC(K)                                                        \
    pr0 = fmaf(g##K, gv##K.x, pr0);                                    \
    pr1 = fmaf(g##K, gv##K.y, pr1);                                    \
    pr2 = fmaf(g##K, gv##K.z, pr2);                                    \
    pr3 = fmaf(g##K, gv##K.w, pr3);

// One time step. WRITES/READS select the parity-transposed layout.
#define STEP(T, WR0, WR1, WR2, WR3, RD0, RD1, RD2, RD3)                  \
    {                                                                    \
        const int t = (T);                                               \
        int   tn  = (t + 1 < T_STEPS) ? t + 1 : t;                       \
        float nx0 = xp[(size_t)tn * BATCH * 3 + 0];                      \
        float nx1 = xp[(size_t)tn * BATCH * 3 + 1];                      \
        float nx2 = xp[(size_t)tn * BATCH * 3 + 2];                      \
                                                                         \
        float pr0 = 0.f, pr1 = 0.f, pr2 = 0.f, pr3 = 0.f;                \
        {                                                                \
            unsigned long long m = bm;                                   \
            while (m) {                                                  \
                GSLOT(0) GSLOT(1) GSLOT(2) GSLOT(3)                      \
                GSLOT(4) GSLOT(5) GSLOT(6) GSLOT(7)                      \
                GACC(0) GACC(1) GACC(2) GACC(3)                          \
                GACC(4) GACC(5) GACC(6) GACC(7)                          \
            }                                                            \
        }                                                                \
                                                                         \
        if (l < 50) { WR0 = pr0; WR1 = pr1; WR2 = pr2; WR3 = pr3; }      \
        BARRIER_LGKM                                                     \
                                                                         \
        float p0 = RD0, p1 = RD1, p2 = RD2, p3 = RD3;                    \
        float rec = ((p0 + p1) + p2) + p3;                               \
                                                                         \
        float c1 = fmaf(x2, w12, fmaf(x1, w11, x0 * w10)) + b1j;         \
        float ba = ((BETA_C * mem + c1) + rec) + brj;                    \
        float nm = (mem > THR_C) ? 0.f : ba;                             \
        float sp = (nm > THR_C) ? 1.f : 0.f;                             \
        mem = nm;                                                        \
                                                                         \
        if (l < 50)                                                      \
            spk_out[(size_t)t * BATCH * NHID] = sp;                      \
        bm = __ballot((l < 50) && (sp > 0.5f));                          \
                                                                         \
        x0 = nx0; x1 = nx1; x2 = nx2;                                    \
    }

    for (int tt = 0; tt < T_STEPS; tt += 2) {
        // even step: write part[c][w], read part[w][s]
        STEP(tt,
             part[0][w][l], part[1][w][l], part[2][w][l], part[3][w][l],
             part[w][0][lc], part[w][1][lc], part[w][2][lc], part[w][3][lc])
        // odd step: write part[w][c], read part[s][w]
        STEP(tt + 1,
             part[w][0][l], part[w][1][l], part[w][2][l], part[w][3][l],
             part[0][w][lc], part[1][w][lc], part[2][w][lc], part[3][w][lc])
    }
#undef STEP
#undef GSLOT
#undef GACC
}

// cur2[t,b] = sum_j spk[t,b,j]*W2[j] + b2 — recomputed from stored spikes
// (L3-resident). Terminal output: tree reduction order is safe.
__launch_bounds__(256)
__global__ void cur2_kernel(const float* __restrict__ spk,
                            const float* __restrict__ W2,
                            const float* __restrict__ b2,
                            float* __restrict__ out) {
    const int lane = threadIdx.x & 63;
    const int wid  = (int)((blockIdx.x * blockDim.x + threadIdx.x) >> 6);
    const int nw   = (int)((gridDim.x * blockDim.x) >> 6);

    float4 w2v = {0.f, 0.f, 0.f, 0.f};
    if (lane < 50) w2v = *(const float4*)(W2 + lane * 4);
    const float b2v = b2[0];

    for (int p = wid; p < T_STEPS * BATCH; p += nw) {
        float4 sv = {0.f, 0.f, 0.f, 0.f};
        if (lane < 50) sv = *(const float4*)(spk + (size_t)p * NHID + lane * 4);
        float a = fmaf(sv.w, w2v.w, fmaf(sv.z, w2v.z,
                  fmaf(sv.y, w2v.y, sv.x * w2v.x)));
#pragma unroll
        for (int o = 32; o >= 1; o >>= 1) a += __shfl_xor(a, o);
        if (lane == 0) out[p] = a + b2v;   // p = t*BATCH + b
    }
}

extern "C" void kernel_launch(void* const* d_in, const int* in_sizes, int n_in,
                              void* d_out, int out_size, void* d_ws, size_t ws_size,
                              hipStream_t stream) {
    const float* X    = (const float*)d_in[0];
    const float* W1   = (const float*)d_in[1];
    const float* b1   = (const float*)d_in[2];
    const float* Wrec = (const float*)d_in[3];
    const float* brec = (const float*)d_in[4];
    const float* W2   = (const float*)d_in[5];
    const float* b2   = (const float*)d_in[6];

    float* out_cur2 = (float*)d_out;                            // [T,B,1] flat
    float* out_spk  = (float*)d_out + (size_t)T_STEPS * BATCH;  // [T,B,200] flat

    rsnn_kernel<<<BATCH, 256, 0, stream>>>(X, W1, b1, Wrec, brec, out_spk);
    cur2_kernel<<<1024, 256, 0, stream>>>(out_spk, W2, b2, out_cur2);
}